// Round 2
// baseline (221.040 us; speedup 1.0000x reference)
//
#include <hip/hip_runtime.h>
#include <hip/hip_bf16.h>

// ---- problem constants ----
#define Bb    2
#define Cc    128
#define HWp   16384    // 128*128 (one channel plane)
#define NBLK  64
#define BNOD  16
#define NPix  256
#define Nn    1024

// ---- ws layout (float element offsets) ----
#define OQ    0u        // Q      [B][NBLK][BNOD][NP]   524288
#define OF    524288u   // feats  [B][N][C]             262144
#define OFR   2883584u  // Fr     [S][B][N][C]          786432
#define OFN   3670016u  // FnT    bf16 [S*B][C][N]      (786432 bf16 = 393216 f-slots)
#define OGI   4456448u  // gi     [S][B][N]               6144
#define OGJ   4462592u  // gj     [S][B][N]               6144
#define OOUT  4468736u  // agg-acc / out [S][B][N][C]   786432
#define OBNS  5255168u  // bn sum [S][C]                   384
#define OBNQ  5255552u  // bn sq  [S][C]                   384
#define OPOOL 5255936u  // pool   [S][B][C]                768
#define OP2   5256704u  // pool2  [S][B][C]                768
#define OYS   5258240u  // ys     [S][B][N][C]          786432
#define OAW   6306816u  // masked-gated W bf16 [6][1024][1024] (3145728 f-slots)
// OFT (featsT f32 [B][C][N]) overlays OYS: live only proj2->fm_adj (OYS written later by k_bn_att).
#define OFT   OYS

typedef short s8v  __attribute__((ext_vector_type(8)));
typedef float f4v  __attribute__((ext_vector_type(4)));

__device__ __forceinline__ short f2bf(float f) {
    __hip_bfloat16 h = __float2bfloat16(f);
    return *reinterpret_cast<short*>(&h);
}

// ---------------- P1: logits + softmax over 16 nodes -> Q ----------------
// 2 pixels/thread: the 16 node-param LDS broadcasts per c now serve 128 cyc of
// fma instead of 64 -> VALU-bound instead of LDS-broadcast-bound.
__global__ __launch_bounds__(256) void k_proj1(const float* __restrict__ x,
                                               const float* __restrict__ anchor,
                                               const float* __restrict__ sigma_raw,
                                               float* __restrict__ ws) {
    const int blk = blockIdx.x, b = blockIdx.y, pg = blockIdx.z;   // pg in {0,1}
    const int t = threadIdx.x;
    if (blk == 0 && b == 0 && pg == 0) {
        for (int i = t; i < 1536; i += 256) ws[OBNS + i] = 0.0f;  // BNS+BNQ+POOL
    }
    __shared__ __align__(16) float2 pairs[128][16];   // 16 KB
    __shared__ float accp[4][128][17];                // 34.8 KB
    for (int e = t; e < 16 * 128; e += 256) {
        int k = e >> 7, c = e & 127;
        int n = blk * 16 + k;
        float a    = anchor[n * 128 + c];
        float sr   = sigma_raw[n * 128 + c];
        float isig = 1.0f + __expf(-sr);       // 1/sigmoid(sr)
        pairs[c][k] = make_float2(isig, a * isig);
    }
    __syncthreads();
    const int pl = t & 63, cq = t >> 6;
    const int p0 = pg * 128 + pl;              // second pixel is p0+64 (4 rows below)
    const int h = (blk >> 3) * 16 + (p0 >> 4);
    const int w = (blk & 7) * 16 + (p0 & 15);
    const float* xp = x + (size_t)b * Cc * HWp + (size_t)h * 128 + w;
    float acc0[16], acc1[16];
#pragma unroll
    for (int k = 0; k < 16; k++) { acc0[k] = 0.0f; acc1[k] = 0.0f; }
    for (int c = cq * 32; c < cq * 32 + 32; c++) {
        float pv0 = xp[(size_t)c * HWp];
        float pv1 = xp[(size_t)c * HWp + 512];   // pixel p0+64: h+4 rows
#pragma unroll
        for (int k = 0; k < 16; k += 2) {
            float4 pr = *(const float4*)&pairs[c][k];   // (is_k, ais_k, is_k1, ais_k1)
            float d00 = fmaf(pv0, pr.x, -pr.y);
            float d01 = fmaf(pv0, pr.z, -pr.w);
            float d10 = fmaf(pv1, pr.x, -pr.y);
            float d11 = fmaf(pv1, pr.z, -pr.w);
            acc0[k]     = fmaf(d00, d00, acc0[k]);
            acc0[k + 1] = fmaf(d01, d01, acc0[k + 1]);
            acc1[k]     = fmaf(d10, d10, acc1[k]);
            acc1[k + 1] = fmaf(d11, d11, acc1[k + 1]);
        }
    }
#pragma unroll
    for (int k = 0; k < 16; k++) {
        accp[cq][pl][k]      = acc0[k];
        accp[cq][64 + pl][k] = acc1[k];
    }
    __syncthreads();
    if (t < 128) {
        float a2[16];
#pragma unroll
        for (int k = 0; k < 16; k++)
            a2[k] = accp[0][t][k] + accp[1][t][k] + accp[2][t][k] + accp[3][t][k];
        float m = a2[0];
#pragma unroll
        for (int k = 1; k < 16; k++) m = fminf(m, a2[k]);
        float ssum = 0.0f, ev[16];
#pragma unroll
        for (int k = 0; k < 16; k++) { ev[k] = __expf(0.5f * (m - a2[k])); ssum += ev[k]; }
        float inv = 1.0f / ssum;
        const int p = pg * 128 + t;
        float* Qp = ws + OQ + ((size_t)(b * 64 + blk) * 16) * 256 + p;
#pragma unroll
        for (int k = 0; k < 16; k++) Qp[k * 256] = ev[k] * inv;
    }
}

// ---------------- P2: nodes -> per-node L2 normalized feats ----------------
// node-half split (kh): 256 blocks of 128 threads -> all 256 CUs busy
// (was 128 blocks / half the chip idle). Same per-thread math/order as before.
__global__ __launch_bounds__(128) void k_proj2(const float* __restrict__ x,
                                               const float* __restrict__ anchor,
                                               const float* __restrict__ sigma_raw,
                                               float* __restrict__ ws) {
    const int blk = blockIdx.x, b = blockIdx.y, kh = blockIdx.z;   // kh in {0,1}
    const int t = threadIdx.x;
    __shared__ __align__(16) float Ql[8][256];     // 8 KB
    __shared__ __align__(16) float pixl[32][260];  // 33.3 KB
    __shared__ float vbuf[8][132];                 // 4.2 KB
    __shared__ float invn[8];
    __shared__ float S0s[8];
    const float* Qg = ws + OQ + (size_t)(b * 64 + blk) * 16 * 256 + (size_t)kh * 8 * 256;
    for (int e = t; e < 512; e += 128)
        *(float4*)&Ql[e >> 6][(e & 63) * 4] = *(const float4*)(Qg + (size_t)e * 4);
    __syncthreads();
    if (t < 8) {
        float s0 = 0.0f;
        for (int pc = 0; pc < 64; pc++) {
            float4 q = *(const float4*)&Ql[t][pc * 4];
            s0 += (q.x + q.y) + (q.z + q.w);
        }
        S0s[t] = s0;
    }
    __syncthreads();
    const int cq = t & 31;
    const int k0 = (t >> 5) * 2;                   // local node pair 0,2,4,6
    const int n0 = blk * 16 + kh * 8 + k0;
    const int h0 = (blk >> 3) * 16, w0 = (blk & 7) * 16;
    const float S0a = S0s[k0], S0b = S0s[k0 + 1];
    const float i0a = 1.0f / (S0a + 1e-9f);
    const float i0b = 1.0f / (S0b + 1e-9f);
    float nsqa = 0.0f, nsqb = 0.0f;
    for (int q = 0; q < 4; q++) {
        const int c = q * 32 + cq;
        __syncthreads();
        for (int e = t; e < 2048; e += 128) {
            int cc = e >> 6, f4 = e & 63;
            int pr = f4 >> 2, wq = (f4 & 3) * 4;
            *(float4*)&pixl[cc][f4 * 4] =
                *(const float4*)(x + ((size_t)b * Cc + q * 32 + cc) * HWp
                                 + (size_t)(h0 + pr) * 128 + w0 + wq);
        }
        __syncthreads();
        float s1a = 0.0f, s1b = 0.0f;
        for (int pc = 0; pc < 64; pc++) {
            float4 pv = *(const float4*)&pixl[cq][pc * 4];
            float4 qa = *(const float4*)&Ql[k0][pc * 4];
            float4 qb = *(const float4*)&Ql[k0 + 1][pc * 4];
            s1a = fmaf(pv.x, qa.x, fmaf(pv.y, qa.y, fmaf(pv.z, qa.z, fmaf(pv.w, qa.w, s1a))));
            s1b = fmaf(pv.x, qb.x, fmaf(pv.y, qb.y, fmaf(pv.z, qb.z, fmaf(pv.w, qb.w, s1b))));
        }
        float isa = 1.0f + __expf(-sigma_raw[(n0)     * 128 + c]);
        float isb = 1.0f + __expf(-sigma_raw[(n0 + 1) * 128 + c]);
        float aa  = anchor[(n0)     * 128 + c];
        float ab  = anchor[(n0 + 1) * 128 + c];
        float va = isa * (s1a - aa * S0a) * i0a;
        float vb = isb * (s1b - ab * S0b) * i0b;
        vbuf[k0][c]     = va;
        vbuf[k0 + 1][c] = vb;
        nsqa = fmaf(va, va, nsqa);
        nsqb = fmaf(vb, vb, nsqb);
    }
#pragma unroll
    for (int off = 16; off >= 1; off >>= 1) {
        nsqa += __shfl_xor(nsqa, off, 64);
        nsqb += __shfl_xor(nsqb, off, 64);
    }
    if (cq == 0) {
        invn[k0]     = 1.0f / fmaxf(sqrtf(nsqa), 1e-12f);
        invn[k0 + 1] = 1.0f / fmaxf(sqrtf(nsqb), 1e-12f);
    }
    __syncthreads();
    for (int e = t; e < 8 * 128; e += 128) {
        int k = e >> 7, c = e & 127;
        ws[OF + ((size_t)b * Nn + blk * 16 + kh * 8 + k) * 128 + c] = vbuf[k][c] * invn[k];
    }
#pragma unroll
    for (int pass = 0; pass < 8; pass++) {
        int k = t & 7, c = (t >> 3) + pass * 16;
        ws[OFT + ((size_t)b * 128 + c) * 1024 + blk * 16 + kh * 8 + k] = vbuf[k][c] * invn[k];
    }
}

// ---------------- merged: feats@W (384 blocks) || adj GEMM + mask/gate -> bf16 W matrices (512 blocks) ----------------
__global__ __launch_bounds__(256) void k_fm_adj(const float* __restrict__ W_root,
                                                const float* __restrict__ W_nbr,
                                                const float* __restrict__ wgs,
                                                const float* __restrict__ wgd,
                                                const float* __restrict__ b_gate,
                                                float* __restrict__ ws) {
    __shared__ __align__(16) float sm[8704];   // 34.8 KB shared by both branches
    const int bid = blockIdx.x;
    const int t = threadIdx.x;
    if (bid < 384) {
        // ---- feat_mm branch ----
        const int tile = bid & 63, b = (bid >> 6) & 1, s = bid >> 7;
        float (*fl)[132] = (float(*)[132])sm;
        const float* F = ws + OF + ((size_t)b * Nn + tile * 16) * 128;
        for (int e = t; e < 16 * 128; e += 256) fl[e >> 7][e & 127] = F[e];
        __syncthreads();
        const int cout = t & 127, ih = t >> 7;
        float ar[8], an[8];
#pragma unroll
        for (int q = 0; q < 8; q++) { ar[q] = 0.0f; an[q] = 0.0f; }
        const float* Wr = W_root + s * 16384;
        const float* Wn = W_nbr + s * 16384;
        for (int cin = 0; cin < 128; cin++) {
            float wr = Wr[cin * 128 + cout];
            float wn = Wn[cin * 128 + cout];
#pragma unroll
            for (int q = 0; q < 8; q++) {
                float f = fl[ih * 8 + q][cin];
                ar[q] = fmaf(f, wr, ar[q]);
                an[q] = fmaf(f, wn, an[q]);
            }
        }
        const int sb = s * 2 + b;
#pragma unroll
        for (int q = 0; q < 8; q++) {
            int row = tile * 16 + ih * 8 + q;
            ws[OFR + ((size_t)sb * Nn + row) * 128 + cout] = ar[q];
        }
        {
            short hb[8];
#pragma unroll
            for (int q = 0; q < 8; q++) hb[q] = f2bf(an[q]);
            short* fnb = (short*)(ws + OFN);
            *(int4*)(fnb + (((size_t)sb * 128 + cout) << 10) + tile * 16 + ih * 8) = *(int4*)hb;
        }
        if (t < 16) {
            int row = tile * 16 + t;
            float g1 = 0.0f, g2 = 0.0f;
            for (int c = 0; c < 128; c++) {
                float f = fl[t][c];
                g1 = fmaf(f, wgs[s * 128 + c], g1);
                g2 = fmaf(f, wgd[s * 128 + c], g2);
            }
            ws[OGI + (size_t)sb * Nn + row] = g1;
            ws[OGJ + (size_t)sb * Nn + row] = g2;
        }
    } else {
        // ---- adj branch: 64x64 cosine tile in registers -> mask+gate -> bf16 W ----
        const int e = bid - 384;
        const int jt = e & 15, it = (e >> 4) & 15, b = e >> 8;
        __shared__ float gis[3][64], gjs[3][64], bgs[3];
        if (t < 192) {
            int s = t >> 6, ii = t & 63;
            gis[s][ii] = ws[OGI + (size_t)(s * 2 + b) * Nn + it * 64 + ii];
            gjs[s][ii] = ws[OGJ + (size_t)(s * 2 + b) * Nn + jt * 64 + ii];
        }
        if (t < 3) bgs[t] = b_gate[t];
        // zero the agg accumulator region (512 blocks x 1536 floats = 786432)
        for (int i = t; i < 1536; i += 256) ws[OOUT + (size_t)e * 1536 + i] = 0.0f;
        float (*FiT)[68] = (float(*)[68])sm;
        float (*FjT)[68] = (float(*)[68])(sm + 4352);
        const float* FT = ws + OFT + (size_t)b * 128 * 1024;
        const int tx = t & 15, ty = t >> 4;
        float acc[4][4];
#pragma unroll
        for (int r = 0; r < 4; r++)
#pragma unroll
            for (int ee = 0; ee < 4; ee++) acc[r][ee] = 0.0f;
        for (int ch = 0; ch < 2; ch++) {
            __syncthreads();
#pragma unroll
            for (int k = 0; k < 4; k++) {
                int idx = k * 256 + t;
                int cc = idx >> 4, n4 = (idx & 15) * 4;
                *(float4*)&FiT[cc][n4] =
                    *(const float4*)(FT + (size_t)(ch * 64 + cc) * 1024 + it * 64 + n4);
                *(float4*)&FjT[cc][n4] =
                    *(const float4*)(FT + (size_t)(ch * 64 + cc) * 1024 + jt * 64 + n4);
            }
            __syncthreads();
            for (int c = 0; c < 64; c++) {
                float4 fi = *(const float4*)&FiT[c][ty * 4];
                float4 fj = *(const float4*)&FjT[c][tx * 4];
                const float fiv[4] = {fi.x, fi.y, fi.z, fi.w};
                const float fjv[4] = {fj.x, fj.y, fj.z, fj.w};
#pragma unroll
                for (int r = 0; r < 4; r++)
#pragma unroll
                    for (int ee = 0; ee < 4; ee++)
                        acc[r][ee] = fmaf(fiv[r], fjv[ee], acc[r][ee]);
            }
        }
        short* AW = (short*)(ws + OAW);
#pragma unroll
        for (int s = 0; s < 3; s++) {
            const int sb = s * 2 + b;
#pragma unroll
            for (int r = 0; r < 4; r++) {
                const int i = it * 64 + ty * 4 + r;
                const int iblk = i >> 4;
                const float giv = gis[s][ty * 4 + r];
                short o[4];
#pragma unroll
                for (int ee = 0; ee < 4; ee++) {
                    const int j = jt * 64 + tx * 4 + ee;
                    float a = acc[r][ee];
                    bool same = iblk == (j >> 4);
                    bool pass;
                    if (s == 0)      pass = (a > 0.7f) && same;
                    else if (s == 1) pass = (a > 0.5f) && !same;
                    else             pass = (a > 0.3f);
                    float g = 1.0f / (1.0f + __expf(-(giv + gjs[s][tx * 4 + ee] + bgs[s])));
                    o[ee] = f2bf(pass ? a * g : 0.0f);
                }
                *(int2*)(AW + (((size_t)sb << 20) + ((size_t)i << 10) + jt * 64 + tx * 4)) = *(int2*)o;
            }
        }
    }
}

// ---------------- MFMA aggregation: agg[sb] = AW[sb][1024x1024] @ Fn[1024x128] ----------------
// grid (32 M-tiles, 2 K-halves, 6 sb); 256 threads (4 waves).
__global__ __launch_bounds__(256) void k_agg(float* __restrict__ ws) {
    const int mt = blockIdx.x, kh = blockIdx.y, sb = blockIdx.z;
    const int t = threadIdx.x;
    const int i0 = mt * 32, j00 = kh * 512;
    __shared__ short A_s[32][136];   // 8.7 KB
    __shared__ short B_s[128][136];  // 34.8 KB
    const short* AWp = (const short*)(ws + OAW) + ((size_t)sb << 20);
    const short* fnb = (const short*)(ws + OFN) + ((size_t)sb * 128 << 10);
    const int wid = t >> 6, lane = t & 63, quad = lane >> 4, l15 = lane & 15;
    f4v acc00 = {0,0,0,0}, acc01 = {0,0,0,0}, acc10 = {0,0,0,0}, acc11 = {0,0,0,0};

    for (int chunk = 0; chunk < 4; chunk++) {
        const int j0 = j00 + chunk * 128;
        __syncthreads();
        // stage A: 32 i x 128 k bf16 (pure copy)
        {
            const int i = t >> 3, kk = (t & 7) << 4;
            const short* src = AWp + ((size_t)(i0 + i) << 10) + j0 + kk;
            *(int4*)&A_s[i][kk]     = *(const int4*)(src);
            *(int4*)&A_s[i][kk + 8] = *(const int4*)(src + 8);
        }
        // stage B: FnT bf16 128 c x 128 k
        {
            const int c = t >> 1, k0l = (t & 1) << 6;
            const short* src = fnb + ((size_t)c << 10) + j0 + k0l;
#pragma unroll
            for (int e = 0; e < 8; e++)
                *(int4*)&B_s[c][k0l + e * 8] = *(const int4*)(src + e * 8);
        }
        __syncthreads();
#pragma unroll
        for (int ks = 0; ks < 4; ks++) {
            const int ko = ks * 32 + quad * 8;
            s8v a0 = *(const s8v*)&A_s[l15][ko];
            s8v a1 = *(const s8v*)&A_s[16 + l15][ko];
            s8v b0 = *(const s8v*)&B_s[wid * 32 + l15][ko];
            s8v b1 = *(const s8v*)&B_s[wid * 32 + 16 + l15][ko];
            acc00 = __builtin_amdgcn_mfma_f32_16x16x32_bf16(a0, b0, acc00, 0, 0, 0);
            acc01 = __builtin_amdgcn_mfma_f32_16x16x32_bf16(a0, b1, acc01, 0, 0, 0);
            acc10 = __builtin_amdgcn_mfma_f32_16x16x32_bf16(a1, b0, acc10, 0, 0, 0);
            acc11 = __builtin_amdgcn_mfma_f32_16x16x32_bf16(a1, b1, acc11, 0, 0, 0);
        }
    }
    {
        float* outp = ws + OOUT + ((size_t)sb * Nn) * 128;
        const int c0 = wid * 32 + l15;
        const int n0 = i0 + quad * 4;
#pragma unroll
        for (int r = 0; r < 4; r++) {
            atomicAdd(outp + (size_t)(n0 + r) * 128 + c0,           acc00[r]);
            atomicAdd(outp + (size_t)(n0 + r) * 128 + c0 + 16,      acc01[r]);
            atomicAdd(outp + (size_t)(n0 + 16 + r) * 128 + c0,      acc10[r]);
            atomicAdd(outp + (size_t)(n0 + 16 + r) * 128 + c0 + 16, acc11[r]);
        }
    }
}

// ---------------- add Fr -> OOUT, BN statistics ----------------
__global__ __launch_bounds__(256) void k_bnstat(float* __restrict__ ws) {
    const int tile = blockIdx.x, b = blockIdx.y, s = blockIdx.z;
    const int sb = s * 2 + b;
    const int t = threadIdx.x;
    __shared__ float bnr[4][128];
    const int c = t & 127, ih = t >> 7;
    const size_t base = ((size_t)sb * Nn + tile * 16) * 128;
    const float* Fr = ws + OFR + base;
    float* outp = ws + OOUT + base;
    float s1 = 0.0f, s2 = 0.0f;
#pragma unroll
    for (int q = 0; q < 8; q++) {
        int idx = (ih * 8 + q) * 128 + c;
        float v = outp[idx] + Fr[idx];
        outp[idx] = v;
        s1 += v;
        s2 = fmaf(v, v, s2);
    }
    bnr[ih][c] = s1;
    bnr[2 + ih][c] = s2;
    __syncthreads();
    if (t < 128) {
        atomicAdd(&ws[OBNS + s * 128 + t], bnr[0][t] + bnr[1][t]);
        atomicAdd(&ws[OBNQ + s * 128 + t], bnr[2][t] + bnr[3][t]);
    }
}

// ---------------- BN + residual + NodeAtt + relu + max-pool ----------------
__global__ __launch_bounds__(256) void k_bn_att(const float* __restrict__ bn_gamma,
                                                const float* __restrict__ bn_beta,
                                                const float* __restrict__ att_W,
                                                const float* __restrict__ att_b,
                                                float* __restrict__ ws) {
    const int tile = blockIdx.x, b = blockIdx.y, s = blockIdx.z;
    const int t = threadIdx.x;
    __shared__ float hl[16][132];
    const int sb = s * 2 + b;
    const int cthr = t & 127, ih = t >> 7;
    float mu = ws[OBNS + s * 128 + cthr] * (1.0f / 2048.0f);
    float ms = ws[OBNQ + s * 128 + cthr] * (1.0f / 2048.0f);
    float var = ms - mu * mu;
    float gam = bn_gamma[s * 128 + cthr];
    float bet = bn_beta[s * 128 + cthr];
    float scal = gam * rsqrtf(var + 1e-5f);
    const float* outp = ws + OOUT + ((size_t)sb * Nn + tile * 16) * 128;
    const float* F = ws + OF + ((size_t)b * Nn + tile * 16) * 128;
#pragma unroll
    for (int q = 0; q < 8; q++) {
        int il = ih * 8 + q;
        float v = outp[(size_t)il * 128 + cthr];
        hl[il][cthr] = scal * (v - mu) + bet + F[(size_t)il * 128 + cthr];
    }
    __syncthreads();
    float acc[8] = {0,0,0,0,0,0,0,0};
    const float* AW = att_W + s * 16384;
    for (int cin = 0; cin < 128; cin++) {
        float w = AW[cin * 128 + cthr];
#pragma unroll
        for (int q = 0; q < 8; q++) acc[q] = fmaf(hl[ih * 8 + q][cin], w, acc[q]);
    }
    float ab = att_b[s * 128 + cthr];
    float* ys = ws + OYS + ((size_t)sb * Nn + tile * 16) * 128;
    float mx = 0.0f;
#pragma unroll
    for (int q = 0; q < 8; q++) {
        int il = ih * 8 + q;
        float h = hl[il][cthr];
        float sg = 1.0f / (1.0f + __expf(-(acc[q] + ab)));
        float y = fmaxf(sg * h, 0.0f);
        ys[(size_t)il * 128 + cthr] = y;
        mx = fmaxf(mx, y);
    }
    atomicMax((unsigned int*)(ws + OPOOL + sb * 128 + cthr), __float_as_uint(mx));
}

// ---------------- pooled MLP (4-way ILP on the serial fma chains) ----------------
__global__ __launch_bounds__(128) void k_mlp(const float* __restrict__ W1, const float* __restrict__ b1,
                                             const float* __restrict__ W2, const float* __restrict__ b2,
                                             float* __restrict__ ws) {
    const int sb = blockIdx.x;      // s*2+b
    const int s = sb >> 1;
    const int t = threadIdx.x;      // cout
    __shared__ float pl[128], z1[128];
    pl[t] = ws[OPOOL + sb * 128 + t];
    __syncthreads();
    {
        float a0 = b1[s * 128 + t], a1 = 0.0f, a2 = 0.0f, a3 = 0.0f;
        const float* W1p = W1 + s * 16384 + t;
        for (int cin = 0; cin < 128; cin += 4) {
            a0 = fmaf(pl[cin],     W1p[(cin)     * 128], a0);
            a1 = fmaf(pl[cin + 1], W1p[(cin + 1) * 128], a1);
            a2 = fmaf(pl[cin + 2], W1p[(cin + 2) * 128], a2);
            a3 = fmaf(pl[cin + 3], W1p[(cin + 3) * 128], a3);
        }
        z1[t] = fmaxf((a0 + a1) + (a2 + a3), 0.0f);
    }
    __syncthreads();
    {
        float a0 = b2[s * 128 + t], a1 = 0.0f, a2 = 0.0f, a3 = 0.0f;
        const float* W2p = W2 + s * 16384 + t;
        for (int cin = 0; cin < 128; cin += 4) {
            a0 = fmaf(z1[cin],     W2p[(cin)     * 128], a0);
            a1 = fmaf(z1[cin + 1], W2p[(cin + 1) * 128], a1);
            a2 = fmaf(z1[cin + 2], W2p[(cin + 2) * 128], a2);
            a3 = fmaf(z1[cin + 3], W2p[(cin + 3) * 128], a3);
        }
        ws[OP2 + sb * 128 + t] = 1.0f / (1.0f + __expf(-((a0 + a1) + (a2 + a3))));
    }
}

// ---------------- fused: coef + combination + lineFu + reprojection + residual (2-way cout split) ----------------
__global__ __launch_bounds__(256) void k_fuse_reproj(const float* __restrict__ lineA_w,
                                                     const float* __restrict__ lineA_b,
                                                     const float* __restrict__ lineFu_W,
                                                     const float* __restrict__ lineFu_b,
                                                     const float* __restrict__ x,
                                                     float* __restrict__ ws,
                                                     float* __restrict__ out) {
    const int tile = blockIdx.x, b = blockIdx.y, chh = blockIdx.z;
    const int t = threadIdx.x;
    __shared__ float fl[16][132];
    __shared__ __align__(16) float ylT[64][20];
    __shared__ float av[3];
    if (t < 3) {
        float acc = lineA_b[t];
        for (int c = 0; c < 128; c++)
            acc = fmaf(ws[OP2 + (t * 2 + b) * 128 + c], lineA_w[t * 128 + c], acc);
        av[t] = acc;
    }
    __syncthreads();
    const float m = fmaxf(av[0], fmaxf(av[1], av[2]));
    const float e0 = __expf(av[0] - m), e1 = __expf(av[1] - m), e2 = __expf(av[2] - m);
    const float sinv = 1.0f / (e0 + e1 + e2);
    const int cthr = t & 127, ih = t >> 7;
    const float c0 = e0 * sinv * ws[OP2 + (0 * 2 + b) * 128 + cthr];
    const float c1 = e1 * sinv * ws[OP2 + (1 * 2 + b) * 128 + cthr];
    const float c2 = e2 * sinv * ws[OP2 + (2 * 2 + b) * 128 + cthr];
#pragma unroll
    for (int q = 0; q < 8; q++) {
        int il = ih * 8 + q;
        size_t row = (size_t)(tile * 16 + il) * 128 + cthr;
        float v = c0 * ws[OYS + (size_t)(0 * 2 + b) * Nn * 128 + row]
                + c1 * ws[OYS + (size_t)(1 * 2 + b) * Nn * 128 + row]
                + c2 * ws[OYS + (size_t)(2 * 2 + b) * Nn * 128 + row];
        fl[il][cthr] = v;
    }
    __syncthreads();
    // lineFu matmul: this block computes couts chh*64..+64; thread = (cout 64, row-group 4)
    {
        const int co = chh * 64 + (t & 63), rg = t >> 6;
        float acc[4] = {0, 0, 0, 0};
        for (int cin = 0; cin < 128; cin++) {
            float w = lineFu_W[cin * 128 + co];
#pragma unroll
            for (int q = 0; q < 4; q++) acc[q] = fmaf(fl[rg * 4 + q][cin], w, acc[q]);
        }
        const float bb = lineFu_b[co];
#pragma unroll
        for (int q = 0; q < 4; q++) ylT[t & 63][rg * 4 + q] = acc[q] + bb;
    }
    // reprojection: thread = pixel, 64 channels of this half
    float qv[16];
    const float* Qg = ws + OQ + (size_t)(b * 64 + tile) * 16 * 256;
#pragma unroll
    for (int k = 0; k < 16; k++) qv[k] = Qg[k * 256 + t];
    __syncthreads();
    const int h = (tile >> 3) * 16 + (t >> 4);
    const int w = (tile & 7) * 16 + (t & 15);
    const float* xp = x + (size_t)b * Cc * HWp + (size_t)h * 128 + w;
    float* op = out + (size_t)b * Cc * HWp + (size_t)h * 128 + w;
    for (int c = 0; c < 64; c++) {
        float4 y0 = *(const float4*)&ylT[c][0];
        float4 y1 = *(const float4*)&ylT[c][4];
        float4 y2 = *(const float4*)&ylT[c][8];
        float4 y3 = *(const float4*)&ylT[c][12];
        float r = 0.0f;
        r = fmaf(qv[0],  y0.x, r); r = fmaf(qv[1],  y0.y, r);
        r = fmaf(qv[2],  y0.z, r); r = fmaf(qv[3],  y0.w, r);
        r = fmaf(qv[4],  y1.x, r); r = fmaf(qv[5],  y1.y, r);
        r = fmaf(qv[6],  y1.z, r); r = fmaf(qv[7],  y1.w, r);
        r = fmaf(qv[8],  y2.x, r); r = fmaf(qv[9],  y2.y, r);
        r = fmaf(qv[10], y2.z, r); r = fmaf(qv[11], y2.w, r);
        r = fmaf(qv[12], y3.x, r); r = fmaf(qv[13], y3.y, r);
        r = fmaf(qv[14], y3.z, r); r = fmaf(qv[15], y3.w, r);
        const size_t off = (size_t)(chh * 64 + c) * HWp;
        op[off] = r + xp[off];
    }
}

extern "C" void kernel_launch(void* const* d_in, const int* in_sizes, int n_in,
                              void* d_out, int out_size, void* d_ws, size_t ws_size,
                              hipStream_t stream) {
    const float* x         = (const float*)d_in[0];
    const float* anchor    = (const float*)d_in[1];
    const float* sigma_raw = (const float*)d_in[2];
    const float* W_root    = (const float*)d_in[3];
    const float* W_nbr     = (const float*)d_in[4];
    const float* wgs       = (const float*)d_in[5];
    const float* wgd       = (const float*)d_in[6];
    const float* b_gate    = (const float*)d_in[7];
    const float* bn_gamma  = (const float*)d_in[8];
    const float* bn_beta   = (const float*)d_in[9];
    const float* att_W     = (const float*)d_in[10];
    const float* att_b     = (const float*)d_in[11];
    const float* mlp_W1    = (const float*)d_in[12];
    const float* mlp_b1    = (const float*)d_in[13];
    const float* mlp_W2    = (const float*)d_in[14];
    const float* mlp_b2    = (const float*)d_in[15];
    const float* lineA_w   = (const float*)d_in[16];
    const float* lineA_b   = (const float*)d_in[17];
    const float* lineFu_W  = (const float*)d_in[18];
    const float* lineFu_b  = (const float*)d_in[19];
    float* out = (float*)d_out;
    float* ws = (float*)d_ws;

    k_proj1      <<<dim3(64, 2, 2), dim3(256), 0, stream>>>(x, anchor, sigma_raw, ws);
    k_proj2      <<<dim3(64, 2, 2), dim3(128), 0, stream>>>(x, anchor, sigma_raw, ws);
    k_fm_adj     <<<dim3(896),      dim3(256), 0, stream>>>(W_root, W_nbr, wgs, wgd, b_gate, ws);
    k_agg        <<<dim3(32, 2, 6), dim3(256), 0, stream>>>(ws);
    k_bnstat     <<<dim3(64, 2, 3), dim3(256), 0, stream>>>(ws);
    k_bn_att     <<<dim3(64, 2, 3), dim3(256), 0, stream>>>(bn_gamma, bn_beta, att_W, att_b, ws);
    k_mlp        <<<dim3(6),        dim3(128), 0, stream>>>(mlp_W1, mlp_b1, mlp_W2, mlp_b2, ws);
    k_fuse_reproj<<<dim3(64, 2, 2), dim3(256), 0, stream>>>(lineA_w, lineA_b, lineFu_W, lineFu_b, x, ws, out);
}

// Round 3
// 220.077 us; speedup vs baseline: 1.0044x; 1.0044x over previous
//
#include <hip/hip_runtime.h>
#include <hip/hip_bf16.h>

// ---- problem constants ----
#define Bb    2
#define Cc    128
#define HWp   16384    // 128*128 (one channel plane)
#define NBLK  64
#define BNOD  16
#define NPix  256
#define Nn    1024

// ---- ws layout (float element offsets) ----
#define OQ    0u        // Q      [B][NBLK][BNOD][NP]   524288
#define OF    524288u   // feats  [B][N][C]             262144
#define OFR   2883584u  // (unused now)
#define OFN   3670016u  // FnT    bf16 [S*B][C][N]      (786432 bf16 = 393216 f-slots)
#define OGI   4456448u  // gi     [S][B][N]               6144
#define OGJ   4462592u  // gj     [S][B][N]               6144
#define OOUT  4468736u  // Fr-init + agg-acc / out [S][B][N][C]   786432
#define OBNS  5255168u  // bn sum [S][C]                   384
#define OBNQ  5255552u  // bn sq  [S][C]                   384
#define OPOOL 5255936u  // pool   [S][B][C]                768
#define OP2   5256704u  // (unused now)
#define OYS   5258240u  // ys     [S][B][N][C]          786432
#define OAW   6306816u  // masked-gated W bf16 [6][1024][1024] (3145728 f-slots)
// OFT (featsT f32 [B][C][N]) overlays OYS: live only proj->fm_adj (OYS written later by k_bn_att).
#define OFT   OYS

typedef short s8v  __attribute__((ext_vector_type(8)));
typedef float f4v  __attribute__((ext_vector_type(4)));

__device__ __forceinline__ short f2bf(float f) {
    __hip_bfloat16 h = __float2bfloat16(f);
    return *reinterpret_cast<short*>(&h);
}

// ---------------- fused P1+P2: logits+softmax -> Q (LDS-resident) -> nodes -> feats ----------------
// One block per (blk,b): proj2's Q dependency is purely intra-block, so Q never
// round-trips through global for phase B. Cuts one dispatch boundary.
__global__ __launch_bounds__(256) void k_proj(const float* __restrict__ x,
                                              const float* __restrict__ anchor,
                                              const float* __restrict__ sigma_raw,
                                              float* __restrict__ ws) {
    const int blk = blockIdx.x, b = blockIdx.y;
    const int t = threadIdx.x;
    // LDS unions: smA = accp[2][128][17] (phase A) | pixl[32][260] (phase B)
    //             smB = pairs[128][16]f2 (phase A inner) | Qs[16][256] (A-end..B)
    __shared__ __align__(16) float smA[8320];   // 33.3 KB
    __shared__ __align__(16) float smB[4096];   // 16 KB
    __shared__ float vbuf[16][132];             // 8.4 KB
    __shared__ float S0s[16];
    __shared__ float invn[16];
    typedef float accp_row[128][17];
    accp_row* accp = (accp_row*)smA;            // accp[ch][pl][k]
    float (*pixl)[260] = (float(*)[260])smA;
    float2 (*pairs)[16] = (float2(*)[16])smB;   // pairs[c][k]
    float (*Qs)[256] = (float(*)[256])smB;      // Qs[k][p]

    if (blk == 0 && b == 0) {
        for (int i = t; i < 1536; i += 256) ws[OBNS + i] = 0.0f;  // BNS+BNQ+POOL
    }
    // ---- phase A: node-distance logits ----
    for (int e = t; e < 2048; e += 256) {
        int k = e >> 7, c = e & 127;
        int n = blk * 16 + k;
        float a    = anchor[n * 128 + c];
        float sr   = sigma_raw[n * 128 + c];
        float isig = 1.0f + __expf(-sr);       // 1/sigmoid(sr)
        pairs[c][k] = make_float2(isig, a * isig);
    }
    __syncthreads();
    const int pl = t & 127, chf = t >> 7;      // 128 pixels x 2 c-halves
    const int h0 = (blk >> 3) * 16, w0 = (blk & 7) * 16;
    const float* xp0 = x + (size_t)b * Cc * HWp
                         + (size_t)(h0 + (pl >> 4)) * 128 + (w0 + (pl & 15));
    float acc0[16], acc1[16];
#pragma unroll
    for (int k = 0; k < 16; k++) { acc0[k] = 0.0f; acc1[k] = 0.0f; }
    for (int c = chf * 64; c < chf * 64 + 64; c++) {
        float pv0 = xp0[(size_t)c * HWp];            // pixel pl        (rows 0-7)
        float pv1 = xp0[(size_t)c * HWp + 1024];     // pixel pl+128    (rows 8-15)
#pragma unroll
        for (int k = 0; k < 16; k += 2) {
            float4 pr = *(const float4*)&pairs[c][k];
            float d00 = fmaf(pv0, pr.x, -pr.y);
            float d01 = fmaf(pv0, pr.z, -pr.w);
            float d10 = fmaf(pv1, pr.x, -pr.y);
            float d11 = fmaf(pv1, pr.z, -pr.w);
            acc0[k]     = fmaf(d00, d00, acc0[k]);
            acc0[k + 1] = fmaf(d01, d01, acc0[k + 1]);
            acc1[k]     = fmaf(d10, d10, acc1[k]);
            acc1[k + 1] = fmaf(d11, d11, acc1[k + 1]);
        }
    }
    // pairs dead from here -> smB becomes Qs.
    float* Qbase = ws + OQ + ((size_t)(b * 64 + blk) * 16) * 256;
#pragma unroll
    for (int pass = 0; pass < 2; pass++) {
#pragma unroll
        for (int k = 0; k < 16; k++) accp[chf][pl][k] = (pass == 0) ? acc0[k] : acc1[k];
        __syncthreads();
        if (t < 128) {
            float a2[16];
#pragma unroll
            for (int k = 0; k < 16; k++) a2[k] = accp[0][t][k] + accp[1][t][k];
            float m = a2[0];
#pragma unroll
            for (int k = 1; k < 16; k++) m = fminf(m, a2[k]);
            float ssum = 0.0f, ev[16];
#pragma unroll
            for (int k = 0; k < 16; k++) { ev[k] = __expf(0.5f * (m - a2[k])); ssum += ev[k]; }
            float inv = 1.0f / ssum;
            const int p = pass * 128 + t;
#pragma unroll
            for (int k = 0; k < 16; k++) {
                float q = ev[k] * inv;
                Qs[k][p] = q;
                Qbase[k * 256 + p] = q;
            }
        }
        __syncthreads();
    }
    // ---- phase B: weighted node residuals + L2 normalize ----
    if (t < 16) {
        float s0 = 0.0f;
        for (int pc = 0; pc < 64; pc++) {
            float4 q = *(const float4*)&Qs[t][pc * 4];
            s0 += (q.x + q.y) + (q.z + q.w);
        }
        S0s[t] = s0;
    }
    __syncthreads();
    const int cq = t & 31;
    const int k0 = (t >> 5) * 2;                   // node pair 0,2,...,14
    const int n0 = blk * 16 + k0;
    const float S0a = S0s[k0], S0b = S0s[k0 + 1];
    const float i0a = 1.0f / (S0a + 1e-9f);
    const float i0b = 1.0f / (S0b + 1e-9f);
    float nsqa = 0.0f, nsqb = 0.0f;
    for (int q = 0; q < 4; q++) {
        const int c = q * 32 + cq;
        __syncthreads();
        for (int e = t; e < 2048; e += 256) {
            int cc = e >> 6, f4 = e & 63;
            int pr = f4 >> 2, wq = (f4 & 3) * 4;
            *(float4*)&pixl[cc][f4 * 4] =
                *(const float4*)(x + ((size_t)b * Cc + q * 32 + cc) * HWp
                                 + (size_t)(h0 + pr) * 128 + w0 + wq);
        }
        __syncthreads();
        float s1a = 0.0f, s1b = 0.0f;
        for (int pc = 0; pc < 64; pc++) {
            float4 pv = *(const float4*)&pixl[cq][pc * 4];
            float4 qa = *(const float4*)&Qs[k0][pc * 4];
            float4 qb = *(const float4*)&Qs[k0 + 1][pc * 4];
            s1a = fmaf(pv.x, qa.x, fmaf(pv.y, qa.y, fmaf(pv.z, qa.z, fmaf(pv.w, qa.w, s1a))));
            s1b = fmaf(pv.x, qb.x, fmaf(pv.y, qb.y, fmaf(pv.z, qb.z, fmaf(pv.w, qb.w, s1b))));
        }
        float isa = 1.0f + __expf(-sigma_raw[(n0)     * 128 + c]);
        float isb = 1.0f + __expf(-sigma_raw[(n0 + 1) * 128 + c]);
        float aa  = anchor[(n0)     * 128 + c];
        float ab  = anchor[(n0 + 1) * 128 + c];
        float va = isa * (s1a - aa * S0a) * i0a;
        float vb = isb * (s1b - ab * S0b) * i0b;
        vbuf[k0][c]     = va;
        vbuf[k0 + 1][c] = vb;
        nsqa = fmaf(va, va, nsqa);
        nsqb = fmaf(vb, vb, nsqb);
    }
#pragma unroll
    for (int off = 16; off >= 1; off >>= 1) {
        nsqa += __shfl_xor(nsqa, off, 64);
        nsqb += __shfl_xor(nsqb, off, 64);
    }
    if (cq == 0) {
        invn[k0]     = 1.0f / fmaxf(sqrtf(nsqa), 1e-12f);
        invn[k0 + 1] = 1.0f / fmaxf(sqrtf(nsqb), 1e-12f);
    }
    __syncthreads();
    for (int e = t; e < 2048; e += 256) {
        int k = e >> 7, c = e & 127;
        ws[OF + ((size_t)b * Nn + blk * 16 + k) * 128 + c] = vbuf[k][c] * invn[k];
    }
#pragma unroll
    for (int pass = 0; pass < 8; pass++) {
        int k = t & 15, c = (t >> 4) + pass * 16;
        ws[OFT + ((size_t)b * 128 + c) * 1024 + blk * 16 + k] = vbuf[k][c] * invn[k];
    }
}

// ---------------- merged: feats@W (384 blocks, Fr -> OOUT init) || adj GEMM + mask/gate -> bf16 W (512 blocks) ----------------
__global__ __launch_bounds__(256) void k_fm_adj(const float* __restrict__ W_root,
                                                const float* __restrict__ W_nbr,
                                                const float* __restrict__ wgs,
                                                const float* __restrict__ wgd,
                                                const float* __restrict__ b_gate,
                                                float* __restrict__ ws) {
    __shared__ __align__(16) float sm[8704];   // 34.8 KB shared by both branches
    const int bid = blockIdx.x;
    const int t = threadIdx.x;
    if (bid < 384) {
        // ---- feat_mm branch ----
        const int tile = bid & 63, b = (bid >> 6) & 1, s = bid >> 7;
        float (*fl)[132] = (float(*)[132])sm;
        const float* F = ws + OF + ((size_t)b * Nn + tile * 16) * 128;
        for (int e = t; e < 16 * 128; e += 256) fl[e >> 7][e & 127] = F[e];
        __syncthreads();
        const int cout = t & 127, ih = t >> 7;
        float ar[8], an[8];
#pragma unroll
        for (int q = 0; q < 8; q++) { ar[q] = 0.0f; an[q] = 0.0f; }
        const float* Wr = W_root + s * 16384;
        const float* Wn = W_nbr + s * 16384;
        for (int cin = 0; cin < 128; cin++) {
            float wr = Wr[cin * 128 + cout];
            float wn = Wn[cin * 128 + cout];
#pragma unroll
            for (int q = 0; q < 8; q++) {
                float f = fl[ih * 8 + q][cin];
                ar[q] = fmaf(f, wr, ar[q]);
                an[q] = fmaf(f, wn, an[q]);
            }
        }
        const int sb = s * 2 + b;
        // Fr written directly as the aggregation accumulator init (no OFR, no zeroing).
#pragma unroll
        for (int q = 0; q < 8; q++) {
            int row = tile * 16 + ih * 8 + q;
            ws[OOUT + ((size_t)sb * Nn + row) * 128 + cout] = ar[q];
        }
        {
            short hb[8];
#pragma unroll
            for (int q = 0; q < 8; q++) hb[q] = f2bf(an[q]);
            short* fnb = (short*)(ws + OFN);
            *(int4*)(fnb + (((size_t)sb * 128 + cout) << 10) + tile * 16 + ih * 8) = *(int4*)hb;
        }
        if (t < 16) {
            int row = tile * 16 + t;
            float g1 = 0.0f, g2 = 0.0f;
            for (int c = 0; c < 128; c++) {
                float f = fl[t][c];
                g1 = fmaf(f, wgs[s * 128 + c], g1);
                g2 = fmaf(f, wgd[s * 128 + c], g2);
            }
            ws[OGI + (size_t)sb * Nn + row] = g1;
            ws[OGJ + (size_t)sb * Nn + row] = g2;
        }
    } else {
        // ---- adj branch: 64x64 cosine tile in registers -> mask+gate -> bf16 W ----
        const int e = bid - 384;
        const int jt = e & 15, it = (e >> 4) & 15, b = e >> 8;
        __shared__ float gis[3][64], gjs[3][64], bgs[3];
        if (t < 192) {
            int s = t >> 6, ii = t & 63;
            gis[s][ii] = ws[OGI + (size_t)(s * 2 + b) * Nn + it * 64 + ii];
            gjs[s][ii] = ws[OGJ + (size_t)(s * 2 + b) * Nn + jt * 64 + ii];
        }
        if (t < 3) bgs[t] = b_gate[t];
        float (*FiT)[68] = (float(*)[68])sm;
        float (*FjT)[68] = (float(*)[68])(sm + 4352);
        const float* FT = ws + OFT + (size_t)b * 128 * 1024;
        const int tx = t & 15, ty = t >> 4;
        float acc[4][4];
#pragma unroll
        for (int r = 0; r < 4; r++)
#pragma unroll
            for (int ee = 0; ee < 4; ee++) acc[r][ee] = 0.0f;
        for (int ch = 0; ch < 2; ch++) {
            __syncthreads();
#pragma unroll
            for (int k = 0; k < 4; k++) {
                int idx = k * 256 + t;
                int cc = idx >> 4, n4 = (idx & 15) * 4;
                *(float4*)&FiT[cc][n4] =
                    *(const float4*)(FT + (size_t)(ch * 64 + cc) * 1024 + it * 64 + n4);
                *(float4*)&FjT[cc][n4] =
                    *(const float4*)(FT + (size_t)(ch * 64 + cc) * 1024 + jt * 64 + n4);
            }
            __syncthreads();
            for (int c = 0; c < 64; c++) {
                float4 fi = *(const float4*)&FiT[c][ty * 4];
                float4 fj = *(const float4*)&FjT[c][tx * 4];
                const float fiv[4] = {fi.x, fi.y, fi.z, fi.w};
                const float fjv[4] = {fj.x, fj.y, fj.z, fj.w};
#pragma unroll
                for (int r = 0; r < 4; r++)
#pragma unroll
                    for (int ee = 0; ee < 4; ee++)
                        acc[r][ee] = fmaf(fiv[r], fjv[ee], acc[r][ee]);
            }
        }
        short* AW = (short*)(ws + OAW);
#pragma unroll
        for (int s = 0; s < 3; s++) {
            const int sb = s * 2 + b;
#pragma unroll
            for (int r = 0; r < 4; r++) {
                const int i = it * 64 + ty * 4 + r;
                const int iblk = i >> 4;
                const float giv = gis[s][ty * 4 + r];
                short o[4];
#pragma unroll
                for (int ee = 0; ee < 4; ee++) {
                    const int j = jt * 64 + tx * 4 + ee;
                    float a = acc[r][ee];
                    bool same = iblk == (j >> 4);
                    bool pass;
                    if (s == 0)      pass = (a > 0.7f) && same;
                    else if (s == 1) pass = (a > 0.5f) && !same;
                    else             pass = (a > 0.3f);
                    float g = 1.0f / (1.0f + __expf(-(giv + gjs[s][tx * 4 + ee] + bgs[s])));
                    o[ee] = f2bf(pass ? a * g : 0.0f);
                }
                *(int2*)(AW + (((size_t)sb << 20) + ((size_t)i << 10) + jt * 64 + tx * 4)) = *(int2*)o;
            }
        }
    }
}

// ---------------- MFMA aggregation: OOUT[sb] += AW[sb][1024x1024] @ Fn[1024x128] ----------------
// grid (32 M-tiles, 2 K-halves, 6 sb); 256 threads (4 waves). OOUT pre-inited with Fr.
__global__ __launch_bounds__(256) void k_agg(float* __restrict__ ws) {
    const int mt = blockIdx.x, kh = blockIdx.y, sb = blockIdx.z;
    const int t = threadIdx.x;
    const int i0 = mt * 32, j00 = kh * 512;
    __shared__ short A_s[32][136];   // 8.7 KB
    __shared__ short B_s[128][136];  // 34.8 KB
    const short* AWp = (const short*)(ws + OAW) + ((size_t)sb << 20);
    const short* fnb = (const short*)(ws + OFN) + ((size_t)sb * 128 << 10);
    const int wid = t >> 6, lane = t & 63, quad = lane >> 4, l15 = lane & 15;
    f4v acc00 = {0,0,0,0}, acc01 = {0,0,0,0}, acc10 = {0,0,0,0}, acc11 = {0,0,0,0};

    for (int chunk = 0; chunk < 4; chunk++) {
        const int j0 = j00 + chunk * 128;
        __syncthreads();
        {
            const int i = t >> 3, kk = (t & 7) << 4;
            const short* src = AWp + ((size_t)(i0 + i) << 10) + j0 + kk;
            *(int4*)&A_s[i][kk]     = *(const int4*)(src);
            *(int4*)&A_s[i][kk + 8] = *(const int4*)(src + 8);
        }
        {
            const int c = t >> 1, k0l = (t & 1) << 6;
            const short* src = fnb + ((size_t)c << 10) + j0 + k0l;
#pragma unroll
            for (int e = 0; e < 8; e++)
                *(int4*)&B_s[c][k0l + e * 8] = *(const int4*)(src + e * 8);
        }
        __syncthreads();
#pragma unroll
        for (int ks = 0; ks < 4; ks++) {
            const int ko = ks * 32 + quad * 8;
            s8v a0 = *(const s8v*)&A_s[l15][ko];
            s8v a1 = *(const s8v*)&A_s[16 + l15][ko];
            s8v b0 = *(const s8v*)&B_s[wid * 32 + l15][ko];
            s8v b1 = *(const s8v*)&B_s[wid * 32 + 16 + l15][ko];
            acc00 = __builtin_amdgcn_mfma_f32_16x16x32_bf16(a0, b0, acc00, 0, 0, 0);
            acc01 = __builtin_amdgcn_mfma_f32_16x16x32_bf16(a0, b1, acc01, 0, 0, 0);
            acc10 = __builtin_amdgcn_mfma_f32_16x16x32_bf16(a1, b0, acc10, 0, 0, 0);
            acc11 = __builtin_amdgcn_mfma_f32_16x16x32_bf16(a1, b1, acc11, 0, 0, 0);
        }
    }
    {
        float* outp = ws + OOUT + ((size_t)sb * Nn) * 128;
        const int c0 = wid * 32 + l15;
        const int n0 = i0 + quad * 4;
#pragma unroll
        for (int r = 0; r < 4; r++) {
            atomicAdd(outp + (size_t)(n0 + r) * 128 + c0,           acc00[r]);
            atomicAdd(outp + (size_t)(n0 + r) * 128 + c0 + 16,      acc01[r]);
            atomicAdd(outp + (size_t)(n0 + 16 + r) * 128 + c0,      acc10[r]);
            atomicAdd(outp + (size_t)(n0 + 16 + r) * 128 + c0 + 16, acc11[r]);
        }
    }
}

// ---------------- BN statistics (read-only reduce over OOUT) ----------------
__global__ __launch_bounds__(256) void k_bnstat(float* __restrict__ ws) {
    const int tile = blockIdx.x, b = blockIdx.y, s = blockIdx.z;
    const int sb = s * 2 + b;
    const int t = threadIdx.x;
    __shared__ float bnr[4][128];
    const int c = t & 127, ih = t >> 7;
    const size_t base = ((size_t)sb * Nn + tile * 16) * 128;
    const float* outp = ws + OOUT + base;
    float s1 = 0.0f, s2 = 0.0f;
#pragma unroll
    for (int q = 0; q < 8; q++) {
        int idx = (ih * 8 + q) * 128 + c;
        float v = outp[idx];
        s1 += v;
        s2 = fmaf(v, v, s2);
    }
    bnr[ih][c] = s1;
    bnr[2 + ih][c] = s2;
    __syncthreads();
    if (t < 128) {
        atomicAdd(&ws[OBNS + s * 128 + t], bnr[0][t] + bnr[1][t]);
        atomicAdd(&ws[OBNQ + s * 128 + t], bnr[2][t] + bnr[3][t]);
    }
}

// ---------------- BN + residual + NodeAtt + relu + max-pool ----------------
__global__ __launch_bounds__(256) void k_bn_att(const float* __restrict__ bn_gamma,
                                                const float* __restrict__ bn_beta,
                                                const float* __restrict__ att_W,
                                                const float* __restrict__ att_b,
                                                float* __restrict__ ws) {
    const int tile = blockIdx.x, b = blockIdx.y, s = blockIdx.z;
    const int t = threadIdx.x;
    __shared__ float hl[16][132];
    const int sb = s * 2 + b;
    const int cthr = t & 127, ih = t >> 7;
    float mu = ws[OBNS + s * 128 + cthr] * (1.0f / 2048.0f);
    float ms = ws[OBNQ + s * 128 + cthr] * (1.0f / 2048.0f);
    float var = ms - mu * mu;
    float gam = bn_gamma[s * 128 + cthr];
    float bet = bn_beta[s * 128 + cthr];
    float scal = gam * rsqrtf(var + 1e-5f);
    const float* outp = ws + OOUT + ((size_t)sb * Nn + tile * 16) * 128;
    const float* F = ws + OF + ((size_t)b * Nn + tile * 16) * 128;
#pragma unroll
    for (int q = 0; q < 8; q++) {
        int il = ih * 8 + q;
        float v = outp[(size_t)il * 128 + cthr];
        hl[il][cthr] = scal * (v - mu) + bet + F[(size_t)il * 128 + cthr];
    }
    __syncthreads();
    float acc[8] = {0,0,0,0,0,0,0,0};
    const float* AW = att_W + s * 16384;
    for (int cin = 0; cin < 128; cin++) {
        float w = AW[cin * 128 + cthr];
#pragma unroll
        for (int q = 0; q < 8; q++) acc[q] = fmaf(hl[ih * 8 + q][cin], w, acc[q]);
    }
    float ab = att_b[s * 128 + cthr];
    float* ys = ws + OYS + ((size_t)sb * Nn + tile * 16) * 128;
    float mx = 0.0f;
#pragma unroll
    for (int q = 0; q < 8; q++) {
        int il = ih * 8 + q;
        float h = hl[il][cthr];
        float sg = 1.0f / (1.0f + __expf(-(acc[q] + ab)));
        float y = fmaxf(sg * h, 0.0f);
        ys[(size_t)il * 128 + cthr] = y;
        mx = fmaxf(mx, y);
    }
    atomicMax((unsigned int*)(ws + OPOOL + sb * 128 + cthr), __float_as_uint(mx));
}

// ---------------- fused: MLP(pool) + coef + combination + lineFu + reprojection + residual ----------------
// k_mlp folded in: every block recomputes P2[3][128] for its b (identical op order
// in every block -> bitwise-consistent). Deletes a 6-block latency-only dispatch.
__global__ __launch_bounds__(256) void k_fuse_reproj(const float* __restrict__ mlp_W1,
                                                     const float* __restrict__ mlp_b1,
                                                     const float* __restrict__ mlp_W2,
                                                     const float* __restrict__ mlp_b2,
                                                     const float* __restrict__ lineA_w,
                                                     const float* __restrict__ lineA_b,
                                                     const float* __restrict__ lineFu_W,
                                                     const float* __restrict__ lineFu_b,
                                                     const float* __restrict__ x,
                                                     float* __restrict__ ws,
                                                     float* __restrict__ out) {
    const int tile = blockIdx.x, b = blockIdx.y, chh = blockIdx.z;
    const int t = threadIdx.x;
    __shared__ float fl[16][132];
    __shared__ __align__(16) float ylT[64][20];
    __shared__ float av[3];
    __shared__ float p2l[3][128];
    __shared__ float poolz[128], z1l[128], zz[2][128];
    const int co = t & 127, hf = t >> 7;
    // ---- MLP prologue: P2 for this b, s = 0..2 ----
    for (int s = 0; s < 3; s++) {
        if (t < 128) poolz[t] = ws[OPOOL + (s * 2 + b) * 128 + t];
        __syncthreads();
        {
            float a = 0.0f;
            const float* W1p = mlp_W1 + s * 16384 + co;
            for (int cin = hf * 64; cin < hf * 64 + 64; cin++)
                a = fmaf(poolz[cin], W1p[cin * 128], a);
            zz[hf][co] = a;
        }
        __syncthreads();
        if (t < 128) z1l[t] = fmaxf(zz[0][t] + zz[1][t] + mlp_b1[s * 128 + t], 0.0f);
        __syncthreads();
        {
            float a = 0.0f;
            const float* W2p = mlp_W2 + s * 16384 + co;
            for (int cin = hf * 64; cin < hf * 64 + 64; cin++)
                a = fmaf(z1l[cin], W2p[cin * 128], a);
            zz[hf][co] = a;   // safe: z1l readers synced above
        }
        __syncthreads();
        if (t < 128)
            p2l[s][t] = 1.0f / (1.0f + __expf(-(zz[0][t] + zz[1][t] + mlp_b2[s * 128 + t])));
        __syncthreads();
    }
    if (t < 3) {
        float acc = lineA_b[t];
        for (int c = 0; c < 128; c++)
            acc = fmaf(p2l[t][c], lineA_w[t * 128 + c], acc);
        av[t] = acc;
    }
    __syncthreads();
    const float m = fmaxf(av[0], fmaxf(av[1], av[2]));
    const float e0 = __expf(av[0] - m), e1 = __expf(av[1] - m), e2 = __expf(av[2] - m);
    const float sinv = 1.0f / (e0 + e1 + e2);
    const int cthr = t & 127, ih = t >> 7;
    const float c0 = e0 * sinv * p2l[0][cthr];
    const float c1 = e1 * sinv * p2l[1][cthr];
    const float c2 = e2 * sinv * p2l[2][cthr];
#pragma unroll
    for (int q = 0; q < 8; q++) {
        int il = ih * 8 + q;
        size_t row = (size_t)(tile * 16 + il) * 128 + cthr;
        float v = c0 * ws[OYS + (size_t)(0 * 2 + b) * Nn * 128 + row]
                + c1 * ws[OYS + (size_t)(1 * 2 + b) * Nn * 128 + row]
                + c2 * ws[OYS + (size_t)(2 * 2 + b) * Nn * 128 + row];
        fl[il][cthr] = v;
    }
    __syncthreads();
    // lineFu matmul: this block computes couts chh*64..+64; thread = (cout 64, row-group 4)
    {
        const int coo = chh * 64 + (t & 63), rg = t >> 6;
        float acc[4] = {0, 0, 0, 0};
        for (int cin = 0; cin < 128; cin++) {
            float w = lineFu_W[cin * 128 + coo];
#pragma unroll
            for (int q = 0; q < 4; q++) acc[q] = fmaf(fl[rg * 4 + q][cin], w, acc[q]);
        }
        const float bb = lineFu_b[coo];
#pragma unroll
        for (int q = 0; q < 4; q++) ylT[t & 63][rg * 4 + q] = acc[q] + bb;
    }
    // reprojection: thread = pixel, 64 channels of this half
    float qv[16];
    const float* Qg = ws + OQ + (size_t)(b * 64 + tile) * 16 * 256;
#pragma unroll
    for (int k = 0; k < 16; k++) qv[k] = Qg[k * 256 + t];
    __syncthreads();
    const int h = (tile >> 3) * 16 + (t >> 4);
    const int w = (tile & 7) * 16 + (t & 15);
    const float* xp = x + (size_t)b * Cc * HWp + (size_t)h * 128 + w;
    float* op = out + (size_t)b * Cc * HWp + (size_t)h * 128 + w;
    for (int c = 0; c < 64; c++) {
        float4 y0 = *(const float4*)&ylT[c][0];
        float4 y1 = *(const float4*)&ylT[c][4];
        float4 y2 = *(const float4*)&ylT[c][8];
        float4 y3 = *(const float4*)&ylT[c][12];
        float r = 0.0f;
        r = fmaf(qv[0],  y0.x, r); r = fmaf(qv[1],  y0.y, r);
        r = fmaf(qv[2],  y0.z, r); r = fmaf(qv[3],  y0.w, r);
        r = fmaf(qv[4],  y1.x, r); r = fmaf(qv[5],  y1.y, r);
        r = fmaf(qv[6],  y1.z, r); r = fmaf(qv[7],  y1.w, r);
        r = fmaf(qv[8],  y2.x, r); r = fmaf(qv[9],  y2.y, r);
        r = fmaf(qv[10], y2.z, r); r = fmaf(qv[11], y2.w, r);
        r = fmaf(qv[12], y3.x, r); r = fmaf(qv[13], y3.y, r);
        r = fmaf(qv[14], y3.z, r); r = fmaf(qv[15], y3.w, r);
        const size_t off = (size_t)(chh * 64 + c) * HWp;
        op[off] = r + xp[off];
    }
}

extern "C" void kernel_launch(void* const* d_in, const int* in_sizes, int n_in,
                              void* d_out, int out_size, void* d_ws, size_t ws_size,
                              hipStream_t stream) {
    const float* x         = (const float*)d_in[0];
    const float* anchor    = (const float*)d_in[1];
    const float* sigma_raw = (const float*)d_in[2];
    const float* W_root    = (const float*)d_in[3];
    const float* W_nbr     = (const float*)d_in[4];
    const float* wgs       = (const float*)d_in[5];
    const float* wgd       = (const float*)d_in[6];
    const float* b_gate    = (const float*)d_in[7];
    const float* bn_gamma  = (const float*)d_in[8];
    const float* bn_beta   = (const float*)d_in[9];
    const float* att_W     = (const float*)d_in[10];
    const float* att_b     = (const float*)d_in[11];
    const float* mlp_W1    = (const float*)d_in[12];
    const float* mlp_b1    = (const float*)d_in[13];
    const float* mlp_W2    = (const float*)d_in[14];
    const float* mlp_b2    = (const float*)d_in[15];
    const float* lineA_w   = (const float*)d_in[16];
    const float* lineA_b   = (const float*)d_in[17];
    const float* lineFu_W  = (const float*)d_in[18];
    const float* lineFu_b  = (const float*)d_in[19];
    float* out = (float*)d_out;
    float* ws = (float*)d_ws;

    k_proj       <<<dim3(64, 2),    dim3(256), 0, stream>>>(x, anchor, sigma_raw, ws);
    k_fm_adj     <<<dim3(896),      dim3(256), 0, stream>>>(W_root, W_nbr, wgs, wgd, b_gate, ws);
    k_agg        <<<dim3(32, 2, 6), dim3(256), 0, stream>>>(ws);
    k_bnstat     <<<dim3(64, 2, 3), dim3(256), 0, stream>>>(ws);
    k_bn_att     <<<dim3(64, 2, 3), dim3(256), 0, stream>>>(bn_gamma, bn_beta, att_W, att_b, ws);
    k_fuse_reproj<<<dim3(64, 2, 2), dim3(256), 0, stream>>>(mlp_W1, mlp_b1, mlp_W2, mlp_b2,
                                                            lineA_w, lineA_b, lineFu_W, lineFu_b,
                                                            x, ws, out);
}

// Round 4
// 219.826 us; speedup vs baseline: 1.0055x; 1.0011x over previous
//
#include <hip/hip_runtime.h>
#include <hip/hip_bf16.h>

// ---- problem constants ----
#define Bb    2
#define Cc    128
#define HWp   16384    // 128*128 (one channel plane)
#define NBLK  64
#define BNOD  16
#define NPix  256
#define Nn    1024

// ---- ws layout (float element offsets) ----
#define OQ    0u        // Q      [B][NBLK][BNOD][NP]   524288
#define OF    524288u   // feats RAW v [B][N][C]        262144  (consumers apply invn)
#define ONSQ  2883584u  // nsq    [B][N]                  2048  (atomic partial sums of v^2)
#define OFN   3670016u  // FnT    bf16 [S*B][C][N]      (786432 bf16 = 393216 f-slots)
#define OGI   4456448u  // gi     [S][B][N]               6144
#define OGJ   4462592u  // gj     [S][B][N]               6144
#define OOUT  4468736u  // Fr-init + agg-acc / out [S][B][N][C]   786432
#define OBNS  5255168u  // bn sum [S][C]                   384
#define OBNQ  5255552u  // bn sq  [S][C]                   384
#define OPOOL 5255936u  // pool   [S][B][C]                768
#define OYS   5258240u  // ys     [S][B][N][C]          786432
#define OAW   6306816u  // masked-gated W bf16 [6][1024][1024] (3145728 f-slots)
// OFT (featsT RAW f32 [B][C][N]) overlays OYS: live only proj2->fm_adj.
#define OFT   OYS

typedef short s8v  __attribute__((ext_vector_type(8)));
typedef float f4v  __attribute__((ext_vector_type(4)));

__device__ __forceinline__ short f2bf(float f) {
    __hip_bfloat16 h = __float2bfloat16(f);
    return *reinterpret_cast<short*>(&h);
}

__device__ __forceinline__ float nrm_inv(float nsq) {
    return 1.0f / fmaxf(sqrtf(nsq), 1e-12f);
}

// ---------------- P1: logits + softmax over 16 nodes -> Q ----------------
// 1024 blocks x 128 threads (32 pixels/block): 4 blocks/CU, latency hidden by TLP.
__global__ __launch_bounds__(128) void k_proj1(const float* __restrict__ x,
                                               const float* __restrict__ anchor,
                                               const float* __restrict__ sigma_raw,
                                               float* __restrict__ ws) {
    const int blk = blockIdx.x, b = blockIdx.y, pg = blockIdx.z;   // pg in 0..7
    const int t = threadIdx.x;
    if (blk == 0 && b == 0 && pg == 0) {
        for (int i = t; i < 1536; i += 128) ws[OBNS + i] = 0.0f;   // BNS+BNQ+POOL
    }
    if (blk == 1 && b == 0 && pg == 0) {
        for (int i = t; i < 2048; i += 128) ws[ONSQ + i] = 0.0f;   // nsq[B][N]
    }
    __shared__ __align__(16) float2 pairs[128][16];   // 16 KB
    __shared__ float accp[4][32][17];                 // 8.7 KB
    for (int e = t; e < 2048; e += 128) {
        int k = e >> 7, c = e & 127;
        int n = blk * 16 + k;
        float a    = anchor[n * 128 + c];
        float sr   = sigma_raw[n * 128 + c];
        float isig = 1.0f + __expf(-sr);       // 1/sigmoid(sr)
        pairs[c][k] = make_float2(isig, a * isig);
    }
    __syncthreads();
    const int pl = t & 31, cq = t >> 5;
    const int p = pg * 32 + pl;
    const int h = (blk >> 3) * 16 + (p >> 4);
    const int w = (blk & 7) * 16 + (p & 15);
    const float* xp = x + (size_t)b * Cc * HWp + (size_t)h * 128 + w;
    float acc[16];
#pragma unroll
    for (int k = 0; k < 16; k++) acc[k] = 0.0f;
    for (int c = cq * 32; c < cq * 32 + 32; c++) {
        float pv = xp[(size_t)c * HWp];
#pragma unroll
        for (int k = 0; k < 16; k += 2) {
            float4 pr = *(const float4*)&pairs[c][k];
            float d0 = fmaf(pv, pr.x, -pr.y);
            float d1 = fmaf(pv, pr.z, -pr.w);
            acc[k]     = fmaf(d0, d0, acc[k]);
            acc[k + 1] = fmaf(d1, d1, acc[k + 1]);
        }
    }
#pragma unroll
    for (int k = 0; k < 16; k++) accp[cq][pl][k] = acc[k];
    __syncthreads();
    if (t < 32) {
        float a2[16];
#pragma unroll
        for (int k = 0; k < 16; k++)
            a2[k] = (accp[0][t][k] + accp[1][t][k]) + (accp[2][t][k] + accp[3][t][k]);
        float m = a2[0];
#pragma unroll
        for (int k = 1; k < 16; k++) m = fminf(m, a2[k]);
        float ssum = 0.0f, ev[16];
#pragma unroll
        for (int k = 0; k < 16; k++) { ev[k] = __expf(0.5f * (m - a2[k])); ssum += ev[k]; }
        float inv = 1.0f / ssum;
        float* Qp = ws + OQ + ((size_t)(b * 64 + blk) * 16) * 256 + (pg * 32 + t);
#pragma unroll
        for (int k = 0; k < 16; k++) Qp[k * 256] = ev[k] * inv;
    }
}

// ---------------- P2: weighted node residuals, RAW v + nsq partials ----------------
// channel-quarter split (cg): 512 blocks x 256 threads, 2 blocks/CU.
// Legal because s1[k][c] is per-channel; only the L2 norm couples channels ->
// emit raw v and atomicAdd nsq[b][n]; consumers apply invn (linear everywhere).
__global__ __launch_bounds__(256) void k_proj2(const float* __restrict__ x,
                                               const float* __restrict__ anchor,
                                               const float* __restrict__ sigma_raw,
                                               float* __restrict__ ws) {
    const int blk = blockIdx.x, b = blockIdx.y, cg = blockIdx.z;   // cg in 0..3
    const int t = threadIdx.x;
    __shared__ __align__(16) float Ql[16][256];    // 16 KB
    __shared__ __align__(16) float pixl[32][260];  // 33.3 KB
    __shared__ float vbuf[16][36];                 // 2.3 KB
    __shared__ float S0s[16];
    const float* Qg = ws + OQ + (size_t)(b * 64 + blk) * 16 * 256;
    for (int e = t; e < 1024; e += 256)
        *(float4*)&Ql[e >> 6][(e & 63) * 4] = *(const float4*)(Qg + (size_t)e * 4);
    __syncthreads();
    if (t < 16) {
        float s0 = 0.0f;
        for (int pc = 0; pc < 64; pc++) {
            float4 q = *(const float4*)&Ql[t][pc * 4];
            s0 += (q.x + q.y) + (q.z + q.w);
        }
        S0s[t] = s0;
    }
    // stage x chunk: channels cg*32..+32, all 256 pixels
    const int h0 = (blk >> 3) * 16, w0 = (blk & 7) * 16;
    for (int e = t; e < 2048; e += 256) {
        int cc = e >> 6, f4 = e & 63;
        int pr = f4 >> 2, wq = (f4 & 3) * 4;
        *(float4*)&pixl[cc][f4 * 4] =
            *(const float4*)(x + ((size_t)b * Cc + cg * 32 + cc) * HWp
                             + (size_t)(h0 + pr) * 128 + w0 + wq);
    }
    __syncthreads();
    const int cq = t & 31;                 // local channel
    const int k0 = (t >> 5) * 2;           // node pair 0,2,...,14
    const int n0 = blk * 16 + k0;
    const int c = cg * 32 + cq;
    const float S0a = S0s[k0], S0b = S0s[k0 + 1];
    const float i0a = 1.0f / (S0a + 1e-9f);
    const float i0b = 1.0f / (S0b + 1e-9f);
    float s1a = 0.0f, s1b = 0.0f;
    for (int pc = 0; pc < 64; pc++) {
        float4 pv = *(const float4*)&pixl[cq][pc * 4];
        float4 qa = *(const float4*)&Ql[k0][pc * 4];
        float4 qb = *(const float4*)&Ql[k0 + 1][pc * 4];
        s1a = fmaf(pv.x, qa.x, fmaf(pv.y, qa.y, fmaf(pv.z, qa.z, fmaf(pv.w, qa.w, s1a))));
        s1b = fmaf(pv.x, qb.x, fmaf(pv.y, qb.y, fmaf(pv.z, qb.z, fmaf(pv.w, qb.w, s1b))));
    }
    float isa = 1.0f + __expf(-sigma_raw[(n0)     * 128 + c]);
    float isb = 1.0f + __expf(-sigma_raw[(n0 + 1) * 128 + c]);
    float aa  = anchor[(n0)     * 128 + c];
    float ab  = anchor[(n0 + 1) * 128 + c];
    float va = isa * (s1a - aa * S0a) * i0a;
    float vb = isb * (s1b - ab * S0b) * i0b;
    // raw v to OF (coalesced per node row)
    ws[OF + ((size_t)b * Nn + n0)     * 128 + c] = va;
    ws[OF + ((size_t)b * Nn + n0 + 1) * 128 + c] = vb;
    vbuf[k0][cq]     = va;
    vbuf[k0 + 1][cq] = vb;
    // nsq partial: reduce over the 32 channels of this wave-half, one atomic per node
    float nsqa = va * va, nsqb = vb * vb;
#pragma unroll
    for (int off = 16; off >= 1; off >>= 1) {
        nsqa += __shfl_xor(nsqa, off, 64);
        nsqb += __shfl_xor(nsqb, off, 64);
    }
    if (cq == 0) {
        atomicAdd(&ws[ONSQ + (size_t)b * Nn + n0],     nsqa);
        atomicAdd(&ws[ONSQ + (size_t)b * Nn + n0 + 1], nsqb);
    }
    __syncthreads();
    // transposed raw v to OFT (16 consecutive nodes per write)
    for (int e = t; e < 512; e += 256) {
        int k = e & 15, cl = e >> 4;
        ws[OFT + ((size_t)b * 128 + cg * 32 + cl) * 1024 + blk * 16 + k] = vbuf[k][cl];
    }
}

// ---------------- merged: feats@W (384 blocks, Fr -> OOUT init) || adj GEMM + mask/gate -> bf16 W (512 blocks) ----------------
// Reads RAW v; applies invn (row-linear for feat_mm/gates, i*j product for adj).
__global__ __launch_bounds__(256) void k_fm_adj(const float* __restrict__ W_root,
                                                const float* __restrict__ W_nbr,
                                                const float* __restrict__ wgs,
                                                const float* __restrict__ wgd,
                                                const float* __restrict__ b_gate,
                                                float* __restrict__ ws) {
    __shared__ __align__(16) float sm[8704];   // 34.8 KB shared by both branches
    const int bid = blockIdx.x;
    const int t = threadIdx.x;
    if (bid < 384) {
        // ---- feat_mm branch ----
        const int tile = bid & 63, b = (bid >> 6) & 1, s = bid >> 7;
        __shared__ float innl[16];
        float (*fl)[132] = (float(*)[132])sm;
        const float* F = ws + OF + ((size_t)b * Nn + tile * 16) * 128;
        for (int e = t; e < 16 * 128; e += 256) fl[e >> 7][e & 127] = F[e];
        if (t < 16) innl[t] = nrm_inv(ws[ONSQ + (size_t)b * Nn + tile * 16 + t]);
        __syncthreads();
        const int cout = t & 127, ih = t >> 7;
        float ar[8], an[8];
#pragma unroll
        for (int q = 0; q < 8; q++) { ar[q] = 0.0f; an[q] = 0.0f; }
        const float* Wr = W_root + s * 16384;
        const float* Wn = W_nbr + s * 16384;
        for (int cin = 0; cin < 128; cin++) {
            float wr = Wr[cin * 128 + cout];
            float wn = Wn[cin * 128 + cout];
#pragma unroll
            for (int q = 0; q < 8; q++) {
                float f = fl[ih * 8 + q][cin];
                ar[q] = fmaf(f, wr, ar[q]);
                an[q] = fmaf(f, wn, an[q]);
            }
        }
        const int sb = s * 2 + b;
        // Fr (with invn applied) written directly as the aggregation accumulator init.
#pragma unroll
        for (int q = 0; q < 8; q++) {
            int row = tile * 16 + ih * 8 + q;
            ws[OOUT + ((size_t)sb * Nn + row) * 128 + cout] = ar[q] * innl[ih * 8 + q];
        }
        {
            short hb[8];
#pragma unroll
            for (int q = 0; q < 8; q++) hb[q] = f2bf(an[q] * innl[ih * 8 + q]);
            short* fnb = (short*)(ws + OFN);
            *(int4*)(fnb + (((size_t)sb * 128 + cout) << 10) + tile * 16 + ih * 8) = *(int4*)hb;
        }
        if (t < 16) {
            int row = tile * 16 + t;
            float g1 = 0.0f, g2 = 0.0f;
            for (int c = 0; c < 128; c++) {
                float f = fl[t][c];
                g1 = fmaf(f, wgs[s * 128 + c], g1);
                g2 = fmaf(f, wgd[s * 128 + c], g2);
            }
            ws[OGI + (size_t)sb * Nn + row] = g1 * innl[t];
            ws[OGJ + (size_t)sb * Nn + row] = g2 * innl[t];
        }
    } else {
        // ---- adj branch: 64x64 cosine tile in registers -> mask+gate -> bf16 W ----
        const int e = bid - 384;
        const int jt = e & 15, it = (e >> 4) & 15, b = e >> 8;
        __shared__ float gis[3][64], gjs[3][64], bgs[3];
        __shared__ float iinv[64], jinv[64];
        if (t < 192) {
            int s = t >> 6, ii = t & 63;
            gis[s][ii] = ws[OGI + (size_t)(s * 2 + b) * Nn + it * 64 + ii];
            gjs[s][ii] = ws[OGJ + (size_t)(s * 2 + b) * Nn + jt * 64 + ii];
        }
        if (t < 3) bgs[t] = b_gate[t];
        if (t >= 192 && t < 256) {
            int ii = t - 192;
            iinv[ii] = nrm_inv(ws[ONSQ + (size_t)b * Nn + it * 64 + ii]);
            jinv[ii] = nrm_inv(ws[ONSQ + (size_t)b * Nn + jt * 64 + ii]);
        }
        float (*FiT)[68] = (float(*)[68])sm;
        float (*FjT)[68] = (float(*)[68])(sm + 4352);
        const float* FT = ws + OFT + (size_t)b * 128 * 1024;
        const int tx = t & 15, ty = t >> 4;
        float acc[4][4];
#pragma unroll
        for (int r = 0; r < 4; r++)
#pragma unroll
            for (int ee = 0; ee < 4; ee++) acc[r][ee] = 0.0f;
        for (int ch = 0; ch < 2; ch++) {
            __syncthreads();
#pragma unroll
            for (int k = 0; k < 4; k++) {
                int idx = k * 256 + t;
                int cc = idx >> 4, n4 = (idx & 15) * 4;
                *(float4*)&FiT[cc][n4] =
                    *(const float4*)(FT + (size_t)(ch * 64 + cc) * 1024 + it * 64 + n4);
                *(float4*)&FjT[cc][n4] =
                    *(const float4*)(FT + (size_t)(ch * 64 + cc) * 1024 + jt * 64 + n4);
            }
            __syncthreads();
            for (int c = 0; c < 64; c++) {
                float4 fi = *(const float4*)&FiT[c][ty * 4];
                float4 fj = *(const float4*)&FjT[c][tx * 4];
                const float fiv[4] = {fi.x, fi.y, fi.z, fi.w};
                const float fjv[4] = {fj.x, fj.y, fj.z, fj.w};
#pragma unroll
                for (int r = 0; r < 4; r++)
#pragma unroll
                    for (int ee = 0; ee < 4; ee++)
                        acc[r][ee] = fmaf(fiv[r], fjv[ee], acc[r][ee]);
            }
        }
        short* AW = (short*)(ws + OAW);
#pragma unroll
        for (int s = 0; s < 3; s++) {
            const int sb = s * 2 + b;
#pragma unroll
            for (int r = 0; r < 4; r++) {
                const int i = it * 64 + ty * 4 + r;
                const int iblk = i >> 4;
                const float giv = gis[s][ty * 4 + r];
                const float ivr = iinv[ty * 4 + r];
                short o[4];
#pragma unroll
                for (int ee = 0; ee < 4; ee++) {
                    const int j = jt * 64 + tx * 4 + ee;
                    float a = acc[r][ee] * ivr * jinv[tx * 4 + ee];
                    bool same = iblk == (j >> 4);
                    bool pass;
                    if (s == 0)      pass = (a > 0.7f) && same;
                    else if (s == 1) pass = (a > 0.5f) && !same;
                    else             pass = (a > 0.3f);
                    float g = 1.0f / (1.0f + __expf(-(giv + gjs[s][tx * 4 + ee] + bgs[s])));
                    o[ee] = f2bf(pass ? a * g : 0.0f);
                }
                *(int2*)(AW + (((size_t)sb << 20) + ((size_t)i << 10) + jt * 64 + tx * 4)) = *(int2*)o;
            }
        }
    }
}

// ---------------- MFMA aggregation: OOUT[sb] += AW[sb][1024x1024] @ Fn[1024x128] ----------------
// grid (32 M-tiles, 4 K-quarters, 6 sb) = 768 blocks (3/CU); 256 threads.
__global__ __launch_bounds__(256) void k_agg(float* __restrict__ ws) {
    const int mt = blockIdx.x, kh = blockIdx.y, sb = blockIdx.z;
    const int t = threadIdx.x;
    const int i0 = mt * 32, j00 = kh * 256;
    __shared__ short A_s[32][136];   // 8.7 KB
    __shared__ short B_s[128][136];  // 34.8 KB
    const short* AWp = (const short*)(ws + OAW) + ((size_t)sb << 20);
    const short* fnb = (const short*)(ws + OFN) + ((size_t)sb * 128 << 10);
    const int wid = t >> 6, lane = t & 63, quad = lane >> 4, l15 = lane & 15;
    f4v acc00 = {0,0,0,0}, acc01 = {0,0,0,0}, acc10 = {0,0,0,0}, acc11 = {0,0,0,0};

    for (int chunk = 0; chunk < 2; chunk++) {
        const int j0 = j00 + chunk * 128;
        __syncthreads();
        {
            const int i = t >> 3, kk = (t & 7) << 4;
            const short* src = AWp + ((size_t)(i0 + i) << 10) + j0 + kk;
            *(int4*)&A_s[i][kk]     = *(const int4*)(src);
            *(int4*)&A_s[i][kk + 8] = *(const int4*)(src + 8);
        }
        {
            const int c = t >> 1, k0l = (t & 1) << 6;
            const short* src = fnb + ((size_t)c << 10) + j0 + k0l;
#pragma unroll
            for (int e = 0; e < 8; e++)
                *(int4*)&B_s[c][k0l + e * 8] = *(const int4*)(src + e * 8);
        }
        __syncthreads();
#pragma unroll
        for (int ks = 0; ks < 4; ks++) {
            const int ko = ks * 32 + quad * 8;
            s8v a0 = *(const s8v*)&A_s[l15][ko];
            s8v a1 = *(const s8v*)&A_s[16 + l15][ko];
            s8v b0 = *(const s8v*)&B_s[wid * 32 + l15][ko];
            s8v b1 = *(const s8v*)&B_s[wid * 32 + 16 + l15][ko];
            acc00 = __builtin_amdgcn_mfma_f32_16x16x32_bf16(a0, b0, acc00, 0, 0, 0);
            acc01 = __builtin_amdgcn_mfma_f32_16x16x32_bf16(a0, b1, acc01, 0, 0, 0);
            acc10 = __builtin_amdgcn_mfma_f32_16x16x32_bf16(a1, b0, acc10, 0, 0, 0);
            acc11 = __builtin_amdgcn_mfma_f32_16x16x32_bf16(a1, b1, acc11, 0, 0, 0);
        }
    }
    {
        float* outp = ws + OOUT + ((size_t)sb * Nn) * 128;
        const int c0 = wid * 32 + l15;
        const int n0 = i0 + quad * 4;
#pragma unroll
        for (int r = 0; r < 4; r++) {
            atomicAdd(outp + (size_t)(n0 + r) * 128 + c0,           acc00[r]);
            atomicAdd(outp + (size_t)(n0 + r) * 128 + c0 + 16,      acc01[r]);
            atomicAdd(outp + (size_t)(n0 + 16 + r) * 128 + c0,      acc10[r]);
            atomicAdd(outp + (size_t)(n0 + 16 + r) * 128 + c0 + 16, acc11[r]);
        }
    }
}

// ---------------- BN statistics (read-only reduce over OOUT) ----------------
__global__ __launch_bounds__(256) void k_bnstat(float* __restrict__ ws) {
    const int tile = blockIdx.x, b = blockIdx.y, s = blockIdx.z;
    const int sb = s * 2 + b;
    const int t = threadIdx.x;
    __shared__ float bnr[4][128];
    const int c = t & 127, ih = t >> 7;
    const size_t base = ((size_t)sb * Nn + tile * 16) * 128;
    const float* outp = ws + OOUT + base;
    float s1 = 0.0f, s2 = 0.0f;
#pragma unroll
    for (int q = 0; q < 8; q++) {
        int idx = (ih * 8 + q) * 128 + c;
        float v = outp[idx];
        s1 += v;
        s2 = fmaf(v, v, s2);
    }
    bnr[ih][c] = s1;
    bnr[2 + ih][c] = s2;
    __syncthreads();
    if (t < 128) {
        atomicAdd(&ws[OBNS + s * 128 + t], bnr[0][t] + bnr[1][t]);
        atomicAdd(&ws[OBNQ + s * 128 + t], bnr[2][t] + bnr[3][t]);
    }
}

// ---------------- BN + residual + NodeAtt + relu + max-pool ----------------
// 8-row tiles: grid (128,2,3) = 768 blocks (3/CU).
__global__ __launch_bounds__(256) void k_bn_att(const float* __restrict__ bn_gamma,
                                                const float* __restrict__ bn_beta,
                                                const float* __restrict__ att_W,
                                                const float* __restrict__ att_b,
                                                float* __restrict__ ws) {
    const int tile8 = blockIdx.x, b = blockIdx.y, s = blockIdx.z;
    const int t = threadIdx.x;
    __shared__ float hl[8][132];
    __shared__ float innl[8];
    const int sb = s * 2 + b;
    const int cthr = t & 127, ih = t >> 7;
    if (t < 8) innl[t] = nrm_inv(ws[ONSQ + (size_t)b * Nn + tile8 * 8 + t]);
    float mu = ws[OBNS + s * 128 + cthr] * (1.0f / 2048.0f);
    float ms = ws[OBNQ + s * 128 + cthr] * (1.0f / 2048.0f);
    float var = ms - mu * mu;
    float gam = bn_gamma[s * 128 + cthr];
    float bet = bn_beta[s * 128 + cthr];
    float scal = gam * rsqrtf(var + 1e-5f);
    const float* outp = ws + OOUT + ((size_t)sb * Nn + tile8 * 8) * 128;
    const float* F = ws + OF + ((size_t)b * Nn + tile8 * 8) * 128;
    __syncthreads();
#pragma unroll
    for (int q = 0; q < 4; q++) {
        int il = ih * 4 + q;
        float v = outp[(size_t)il * 128 + cthr];
        hl[il][cthr] = scal * (v - mu) + bet + F[(size_t)il * 128 + cthr] * innl[il];
    }
    __syncthreads();
    float acc[4] = {0, 0, 0, 0};
    const float* AW = att_W + s * 16384;
    for (int cin = 0; cin < 128; cin++) {
        float w = AW[cin * 128 + cthr];
#pragma unroll
        for (int q = 0; q < 4; q++) acc[q] = fmaf(hl[ih * 4 + q][cin], w, acc[q]);
    }
    float ab = att_b[s * 128 + cthr];
    float* ys = ws + OYS + ((size_t)sb * Nn + tile8 * 8) * 128;
    float mx = 0.0f;
#pragma unroll
    for (int q = 0; q < 4; q++) {
        int il = ih * 4 + q;
        float h = hl[il][cthr];
        float sg = 1.0f / (1.0f + __expf(-(acc[q] + ab)));
        float y = fmaxf(sg * h, 0.0f);
        ys[(size_t)il * 128 + cthr] = y;
        mx = fmaxf(mx, y);
    }
    atomicMax((unsigned int*)(ws + OPOOL + sb * 128 + cthr), __float_as_uint(mx));
}

// ---------------- fused: MLP(pool) + coef + combination + lineFu + reprojection + residual ----------------
// chh 0..3 (32-cout quarters): grid (64,2,4) = 512 blocks (2/CU).
__global__ __launch_bounds__(256) void k_fuse_reproj(const float* __restrict__ mlp_W1,
                                                     const float* __restrict__ mlp_b1,
                                                     const float* __restrict__ mlp_W2,
                                                     const float* __restrict__ mlp_b2,
                                                     const float* __restrict__ lineA_w,
                                                     const float* __restrict__ lineA_b,
                                                     const float* __restrict__ lineFu_W,
                                                     const float* __restrict__ lineFu_b,
                                                     const float* __restrict__ x,
                                                     float* __restrict__ ws,
                                                     float* __restrict__ out) {
    const int tile = blockIdx.x, b = blockIdx.y, chh = blockIdx.z;
    const int t = threadIdx.x;
    __shared__ float fl[16][132];
    __shared__ __align__(16) float ylT[32][20];
    __shared__ float av[3];
    __shared__ float p2l[3][128];
    __shared__ float poolz[128], z1l[128], zz[2][128];
    const int co = t & 127, hf = t >> 7;
    // ---- MLP prologue: P2 for this b, s = 0..2 (recomputed per block, bitwise-consistent) ----
    for (int s = 0; s < 3; s++) {
        if (t < 128) poolz[t] = ws[OPOOL + (s * 2 + b) * 128 + t];
        __syncthreads();
        {
            float a = 0.0f;
            const float* W1p = mlp_W1 + s * 16384 + co;
            for (int cin = hf * 64; cin < hf * 64 + 64; cin++)
                a = fmaf(poolz[cin], W1p[cin * 128], a);
            zz[hf][co] = a;
        }
        __syncthreads();
        if (t < 128) z1l[t] = fmaxf(zz[0][t] + zz[1][t] + mlp_b1[s * 128 + t], 0.0f);
        __syncthreads();
        {
            float a = 0.0f;
            const float* W2p = mlp_W2 + s * 16384 + co;
            for (int cin = hf * 64; cin < hf * 64 + 64; cin++)
                a = fmaf(z1l[cin], W2p[cin * 128], a);
            zz[hf][co] = a;
        }
        __syncthreads();
        if (t < 128)
            p2l[s][t] = 1.0f / (1.0f + __expf(-(zz[0][t] + zz[1][t] + mlp_b2[s * 128 + t])));
        __syncthreads();
    }
    if (t < 3) {
        float acc = lineA_b[t];
        for (int c = 0; c < 128; c++)
            acc = fmaf(p2l[t][c], lineA_w[t * 128 + c], acc);
        av[t] = acc;
    }
    __syncthreads();
    const float m = fmaxf(av[0], fmaxf(av[1], av[2]));
    const float e0 = __expf(av[0] - m), e1 = __expf(av[1] - m), e2 = __expf(av[2] - m);
    const float sinv = 1.0f / (e0 + e1 + e2);
    const int cthr = t & 127, ih = t >> 7;
    const float c0 = e0 * sinv * p2l[0][cthr];
    const float c1 = e1 * sinv * p2l[1][cthr];
    const float c2 = e2 * sinv * p2l[2][cthr];
#pragma unroll
    for (int q = 0; q < 8; q++) {
        int il = ih * 8 + q;
        size_t row = (size_t)(tile * 16 + il) * 128 + cthr;
        float v = c0 * ws[OYS + (size_t)(0 * 2 + b) * Nn * 128 + row]
                + c1 * ws[OYS + (size_t)(1 * 2 + b) * Nn * 128 + row]
                + c2 * ws[OYS + (size_t)(2 * 2 + b) * Nn * 128 + row];
        fl[il][cthr] = v;
    }
    __syncthreads();
    // lineFu matmul: this block computes couts chh*32..+32; thread = (cout 32, row-group 8x2)
    {
        const int coo = chh * 32 + (t & 31), rg = t >> 5;
        float acc[2] = {0, 0};
        for (int cin = 0; cin < 128; cin++) {
            float w = lineFu_W[cin * 128 + coo];
#pragma unroll
            for (int q = 0; q < 2; q++) acc[q] = fmaf(fl[rg * 2 + q][cin], w, acc[q]);
        }
        const float bb = lineFu_b[coo];
#pragma unroll
        for (int q = 0; q < 2; q++) ylT[t & 31][rg * 2 + q] = acc[q] + bb;
    }
    // reprojection: thread = pixel, 32 channels of this quarter
    float qv[16];
    const float* Qg = ws + OQ + (size_t)(b * 64 + tile) * 16 * 256;
#pragma unroll
    for (int k = 0; k < 16; k++) qv[k] = Qg[k * 256 + t];
    __syncthreads();
    const int h = (tile >> 3) * 16 + (t >> 4);
    const int w = (tile & 7) * 16 + (t & 15);
    const float* xp = x + (size_t)b * Cc * HWp + (size_t)h * 128 + w;
    float* op = out + (size_t)b * Cc * HWp + (size_t)h * 128 + w;
    for (int c = 0; c < 32; c++) {
        float4 y0 = *(const float4*)&ylT[c][0];
        float4 y1 = *(const float4*)&ylT[c][4];
        float4 y2 = *(const float4*)&ylT[c][8];
        float4 y3 = *(const float4*)&ylT[c][12];
        float r = 0.0f;
        r = fmaf(qv[0],  y0.x, r); r = fmaf(qv[1],  y0.y, r);
        r = fmaf(qv[2],  y0.z, r); r = fmaf(qv[3],  y0.w, r);
        r = fmaf(qv[4],  y1.x, r); r = fmaf(qv[5],  y1.y, r);
        r = fmaf(qv[6],  y1.z, r); r = fmaf(qv[7],  y1.w, r);
        r = fmaf(qv[8],  y2.x, r); r = fmaf(qv[9],  y2.y, r);
        r = fmaf(qv[10], y2.z, r); r = fmaf(qv[11], y2.w, r);
        r = fmaf(qv[12], y3.x, r); r = fmaf(qv[13], y3.y, r);
        r = fmaf(qv[14], y3.z, r); r = fmaf(qv[15], y3.w, r);
        const size_t off = (size_t)(chh * 32 + c) * HWp;
        op[off] = r + xp[off];
    }
}

extern "C" void kernel_launch(void* const* d_in, const int* in_sizes, int n_in,
                              void* d_out, int out_size, void* d_ws, size_t ws_size,
                              hipStream_t stream) {
    const float* x         = (const float*)d_in[0];
    const float* anchor    = (const float*)d_in[1];
    const float* sigma_raw = (const float*)d_in[2];
    const float* W_root    = (const float*)d_in[3];
    const float* W_nbr     = (const float*)d_in[4];
    const float* wgs       = (const float*)d_in[5];
    const float* wgd       = (const float*)d_in[6];
    const float* b_gate    = (const float*)d_in[7];
    const float* bn_gamma  = (const float*)d_in[8];
    const float* bn_beta   = (const float*)d_in[9];
    const float* att_W     = (const float*)d_in[10];
    const float* att_b     = (const float*)d_in[11];
    const float* mlp_W1    = (const float*)d_in[12];
    const float* mlp_b1    = (const float*)d_in[13];
    const float* mlp_W2    = (const float*)d_in[14];
    const float* mlp_b2    = (const float*)d_in[15];
    const float* lineA_w   = (const float*)d_in[16];
    const float* lineA_b   = (const float*)d_in[17];
    const float* lineFu_W  = (const float*)d_in[18];
    const float* lineFu_b  = (const float*)d_in[19];
    float* out = (float*)d_out;
    float* ws = (float*)d_ws;

    k_proj1      <<<dim3(64, 2, 8),  dim3(128), 0, stream>>>(x, anchor, sigma_raw, ws);
    k_proj2      <<<dim3(64, 2, 4),  dim3(256), 0, stream>>>(x, anchor, sigma_raw, ws);
    k_fm_adj     <<<dim3(896),       dim3(256), 0, stream>>>(W_root, W_nbr, wgs, wgd, b_gate, ws);
    k_agg        <<<dim3(32, 4, 6),  dim3(256), 0, stream>>>(ws);
    k_bnstat     <<<dim3(64, 2, 3),  dim3(256), 0, stream>>>(ws);
    k_bn_att     <<<dim3(128, 2, 3), dim3(256), 0, stream>>>(bn_gamma, bn_beta, att_W, att_b, ws);
    k_fuse_reproj<<<dim3(64, 2, 4),  dim3(256), 0, stream>>>(mlp_W1, mlp_b1, mlp_W2, mlp_b2,
                                                             lineA_w, lineA_b, lineFu_W, lineFu_b,
                                                             x, ws, out);
}